// Round 2
// baseline (192.108 us; speedup 1.0000x reference)
//
#include <hip/hip_runtime.h>

#define LROW 136   // padded LDS row stride in bf16 elements (128 + 8)

typedef __bf16 bf16x8 __attribute__((ext_vector_type(8)));
typedef float  f32x4  __attribute__((ext_vector_type(4)));

#define MFMA16(a, b, c) __builtin_amdgcn_mfma_f32_16x16x32_bf16((a), (b), (c), 0, 0, 0)

__device__ __forceinline__ unsigned short f2bf(float f) {
  unsigned u = __float_as_uint(f);
  u += 0x7fffu + ((u >> 16) & 1u);          // round-to-nearest-even
  return (unsigned short)(u >> 16);
}
__device__ __forceinline__ float bflo(unsigned v) { return __uint_as_float(v << 16); }
__device__ __forceinline__ float bfhi(unsigned v) { return __uint_as_float(v & 0xffff0000u); }

// ---------------------------------------------------------------------------
// Kernel 1: fold linear layers into combined weight matrices (bf16, transposed
// [n][k] layout for direct MFMA B-fragment loads) + folded bias vectors (f32).
//   WA = pre_W2 @ msg_W1[0:128]     WB = pre_W2 @ msg_W1[128:256]
//   WD = pre_W2 @ post_W1[128:256]  WC = msg_W2 @ post_W1[0:128]
//   WO = post_W2 @ out_W1           Wo2T = out_W2^T
//   vecs = [w1d | cAB | cP | cO]
// ---------------------------------------------------------------------------
__global__ void combine_weights(
    const float* __restrict__ pre_W2, const float* __restrict__ msg_W1,
    const float* __restrict__ msg_W2, const float* __restrict__ post_W1,
    const float* __restrict__ post_W2, const float* __restrict__ out_W1,
    const float* __restrict__ out_W2, const float* __restrict__ pre_b2,
    const float* __restrict__ msg_b1, const float* __restrict__ msg_b2,
    const float* __restrict__ post_b1, const float* __restrict__ post_b2,
    const float* __restrict__ out_b1,
    unsigned short* __restrict__ WabT, unsigned short* __restrict__ WdT,
    unsigned short* __restrict__ WcT, unsigned short* __restrict__ WoT,
    unsigned short* __restrict__ Wo2T, float* __restrict__ vecs)
{
  const int b = blockIdx.x;
  const int t = threadIdx.x;
  if (b < 320) {
    const int p  = b >> 6;            // which product
    const int kp = b & 63;            // k row-pair
    const int k  = kp * 2 + (t >> 7);
    const int n  = t & 127;
    const float* L; const float* R; unsigned short* O;
    if (p == 0)      { L = pre_W2;  R = msg_W1;             O = WabT; }
    else if (p == 1) { L = pre_W2;  R = msg_W1 + 128*128;   O = WabT + 128*128; }
    else if (p == 2) { L = pre_W2;  R = post_W1 + 128*128;  O = WdT; }
    else if (p == 3) { L = msg_W2;  R = post_W1;            O = WcT; }
    else             { L = post_W2; R = out_W1;             O = WoT; }
    const float* Lr = L + k * 128;
    float a0 = 0.f, a1 = 0.f, a2 = 0.f, a3 = 0.f;
    #pragma unroll 4
    for (int m = 0; m < 128; m += 4) {
      a0 = fmaf(Lr[m + 0], R[(m + 0) * 128 + n], a0);
      a1 = fmaf(Lr[m + 1], R[(m + 1) * 128 + n], a1);
      a2 = fmaf(Lr[m + 2], R[(m + 2) * 128 + n], a2);
      a3 = fmaf(Lr[m + 3], R[(m + 3) * 128 + n], a3);
    }
    O[n * 128 + k] = f2bf((a0 + a1) + (a2 + a3));
  } else {
    // block 320: out_W2 transpose + folded bias vectors
    for (int idx = t; idx < 16 * 128; idx += 256) {
      int o = idx >> 7, k = idx & 127;
      Wo2T[o * 128 + k] = f2bf(out_W2[k * 16 + o]);
    }
    if (t < 128) {
      const int n = t;
      vecs[n] = msg_W1[256 * 128 + n];                    // w1d
      float cab = msg_b1[n];                              // pre_b2@(W1a+W1b)+msg_b1
      float cp  = post_b1[n];                             // 7*msg_b2@P1a + pre_b2@P1b + post_b1
      float co  = out_b1[n];                              // 8*post_b2@out_W1 + out_b1
      for (int m = 0; m < 128; ++m) {
        cab = fmaf(pre_b2[m], msg_W1[m*128 + n] + msg_W1[(128+m)*128 + n], cab);
        cp  = fmaf(7.f * msg_b2[m], post_W1[m*128 + n], cp);
        cp  = fmaf(pre_b2[m], post_W1[(128+m)*128 + n], cp);
        co  = fmaf(8.f * post_b2[m], out_W1[m*128 + n], co);
      }
      vecs[128 + n] = cab;
      vecs[256 + n] = cp;
      vecs[384 + n] = co;
    }
  }
}

// ---------------------------------------------------------------------------
// Kernel 2: fully fused RRN. One block = 8 graphs = 64 node-rows.
// ---------------------------------------------------------------------------
__global__ void __launch_bounds__(256, 2) rrn_main(
    const int* __restrict__ anchors, const int* __restrict__ n_jumps,
    const float* __restrict__ positions, const int* __restrict__ colors,
    const int* __restrict__ markers, const float* __restrict__ pre_W1,
    const float* __restrict__ pre_b1,
    const unsigned short* __restrict__ WabT, const unsigned short* __restrict__ WdT,
    const unsigned short* __restrict__ WcT, const unsigned short* __restrict__ WoT,
    const unsigned short* __restrict__ Wo2T, const float* __restrict__ vecs,
    const float* __restrict__ out_b2, float* __restrict__ out)
{
  __shared__ __align__(16) char smem[65024];
  unsigned short* h1  = (unsigned short*)(smem);            // [64][LROW] bf16; later S
  unsigned short* Ab  = (unsigned short*)(smem + 17408);    // [64][LROW] bf16
  unsigned short* Bb  = (unsigned short*)(smem + 34816);    // [64][LROW] bf16
  float* vec          = (float*)(smem + 52224);             // 512 f32: w1d|cAB|cP|cO
  float* dist         = (float*)(smem + 54272);             // [8][8][8] f32
  unsigned short* Sph = (unsigned short*)(smem + 56320);    // [16][LROW] bf16
  unsigned short* hob = (unsigned short*)(smem + 60672);    // [16][LROW] bf16
  float* sW1          = (float*)(smem + 17408);             // alias over Ab/Bb: 43*128 f32

  const int tid  = threadIdx.x;
  const int lane = tid & 63;
  const int w    = tid >> 6;      // wave 0..3
  const int l15  = lane & 15;
  const int quad = lane >> 4;
  const int g0   = blockIdx.x * 8;   // global graph base
  const int n0   = blockIdx.x * 64;  // global node base

  // ---- phase 0: stage pre_W1+b1, vectors, pairwise distances, zero Sph pad rows
  for (int i = tid; i < 43 * 128; i += 256)
    sW1[i] = (i < 42 * 128) ? pre_W1[i] : pre_b1[i - 42 * 128];
  for (int i = tid; i < 512; i += 256) vec[i] = vecs[i];
  for (int i = tid; i < 512; i += 256) {
    int g = i >> 6, ii = (i >> 3) & 7, jj = i & 7;
    const float* pa = positions + (n0 + g * 8 + ii) * 2;
    const float* pb = positions + (n0 + g * 8 + jj) * 2;
    float dx = pa[0] - pb[0], dy = pa[1] - pb[1];
    dist[i] = sqrtf(dx * dx + dy * dy);
  }
  {
    unsigned* z = (unsigned*)(Sph + 8 * LROW);
    for (int i = tid; i < (8 * LROW) / 2; i += 256) z[i] = 0u;
  }
  __syncthreads();

  // ---- phase 1: h1 = relu(feat @ pre_W1 + pre_b1) via one-hot gathers
  {
    const int n  = tid & 127;
    const int rh = tid >> 7;
    for (int rr = 0; rr < 32; ++rr) {
      int r = rh * 32 + rr;
      int node = n0 + r;
      int g = g0 + (r >> 3);
      float px = positions[node * 2], py = positions[node * 2 + 1];
      int c = colors[node], mk = markers[node] - 8;
      int a = anchors[g], nj = n_jumps[g];
      float acc = sW1[42 * 128 + n]
                + px * sW1[0 * 128 + n] + py * sW1[1 * 128 + n]
                + sW1[(2 + c) * 128 + n] + sW1[(10 + mk) * 128 + n]
                + sW1[(18 + a) * 128 + n] + sW1[(34 + nj) * 128 + n];
      h1[r * LROW + n] = f2bf(fmaxf(acc, 0.f));
    }
  }
  __syncthreads();

  // ---- phase 2: [A|B|D] = h1 @ [WA|WB|WD]   (M=64, N=384, K=128)
  f32x4 accAB[4][4];   // wave's 64 cols of A|B
  f32x4 accD[4][2];    // wave's 32 cols of D (lives until phase 5)
  {
    f32x4 zero = {0.f, 0.f, 0.f, 0.f};
    #pragma unroll
    for (int mt = 0; mt < 4; ++mt) {
      #pragma unroll
      for (int nt = 0; nt < 4; ++nt) accAB[mt][nt] = zero;
      accD[mt][0] = zero; accD[mt][1] = zero;
    }
  }
  #pragma unroll
  for (int kb = 0; kb < 128; kb += 32) {
    const int ko = kb + quad * 8;
    bf16x8 fa[4], fb[4], fd[2];
    #pragma unroll
    for (int mt = 0; mt < 4; ++mt)
      fa[mt] = *(const bf16x8*)&h1[(mt * 16 + l15) * LROW + ko];
    #pragma unroll
    for (int nt = 0; nt < 4; ++nt)
      fb[nt] = *(const bf16x8*)&WabT[(w * 64 + nt * 16 + l15) * 128 + ko];
    #pragma unroll
    for (int dt = 0; dt < 2; ++dt)
      fd[dt] = *(const bf16x8*)&WdT[(w * 32 + dt * 16 + l15) * 128 + ko];
    #pragma unroll
    for (int mt = 0; mt < 4; ++mt) {
      #pragma unroll
      for (int nt = 0; nt < 4; ++nt)
        accAB[mt][nt] = MFMA16(fa[mt], fb[nt], accAB[mt][nt]);
      accD[mt][0] = MFMA16(fa[mt], fd[0], accD[mt][0]);
      accD[mt][1] = MFMA16(fa[mt], fd[1], accD[mt][1]);
    }
  }
  {
    unsigned short* dstbuf = (w < 2) ? Ab : Bb;
    const int cb = (w & 1) * 64;
    #pragma unroll
    for (int mt = 0; mt < 4; ++mt)
      #pragma unroll
      for (int nt = 0; nt < 4; ++nt) {
        int col = cb + nt * 16 + l15;
        #pragma unroll
        for (int r = 0; r < 4; ++r)
          dstbuf[(mt * 16 + quad * 4 + r) * LROW + col] = f2bf(accAB[mt][nt][r]);
      }
  }
  __syncthreads();

  // ---- phase 4: edges. S[i] = sum_{j!=i} relu(A[i]+B[j]+d_ij*w1d+cAB); S -> h1 buf
  {
    unsigned short* Sb = h1;
    const int g   = tid >> 5;          // graph 0..7
    const int nb4 = (tid & 31) * 4;    // 4 hidden dims per thread
    const float4 w1d4 = *(const float4*)&vec[nb4];
    const float4 cab4 = *(const float4*)&vec[128 + nb4];
    float B0[8], B1[8], B2[8], B3[8];
    #pragma unroll
    for (int j = 0; j < 8; ++j) {
      uint2 vb = *(const uint2*)&Bb[(g * 8 + j) * LROW + nb4];
      B0[j] = bflo(vb.x); B1[j] = bfhi(vb.x);
      B2[j] = bflo(vb.y); B3[j] = bfhi(vb.y);
    }
    #pragma unroll
    for (int i = 0; i < 8; ++i) {
      uint2 va = *(const uint2*)&Ab[(g * 8 + i) * LROW + nb4];
      float a0 = bflo(va.x) + cab4.x, a1 = bfhi(va.x) + cab4.y;
      float a2 = bflo(va.y) + cab4.z, a3 = bfhi(va.y) + cab4.w;
      float s0 = 0.f, s1 = 0.f, s2 = 0.f, s3 = 0.f;
      #pragma unroll
      for (int j = 0; j < 8; ++j) {
        if (j == i) continue;
        float d = dist[g * 64 + i * 8 + j];
        s0 += fmaxf(fmaf(d, w1d4.x, B0[j]) + a0, 0.f);
        s1 += fmaxf(fmaf(d, w1d4.y, B1[j]) + a1, 0.f);
        s2 += fmaxf(fmaf(d, w1d4.z, B2[j]) + a2, 0.f);
        s3 += fmaxf(fmaf(d, w1d4.w, B3[j]) + a3, 0.f);
      }
      uint2 o;
      o.x = (unsigned)f2bf(s0) | ((unsigned)f2bf(s1) << 16);
      o.y = (unsigned)f2bf(s2) | ((unsigned)f2bf(s3) << 16);
      *(uint2*)&Sb[(g * 8 + i) * LROW + nb4] = o;
    }
  }
  __syncthreads();

  // ---- phase 5: ph = relu(S@Wc + D + cP); per-graph sum -> Sph (bf16)
  {
    const unsigned short* Sb = h1;
    #pragma unroll
    for (int kb = 0; kb < 128; kb += 32) {
      const int ko = kb + quad * 8;
      bf16x8 fa[4], fc[2];
      #pragma unroll
      for (int mt = 0; mt < 4; ++mt)
        fa[mt] = *(const bf16x8*)&Sb[(mt * 16 + l15) * LROW + ko];
      #pragma unroll
      for (int dt = 0; dt < 2; ++dt)
        fc[dt] = *(const bf16x8*)&WcT[(w * 32 + dt * 16 + l15) * 128 + ko];
      #pragma unroll
      for (int mt = 0; mt < 4; ++mt) {
        accD[mt][0] = MFMA16(fa[mt], fc[0], accD[mt][0]);
        accD[mt][1] = MFMA16(fa[mt], fc[1], accD[mt][1]);
      }
    }
    #pragma unroll
    for (int mt = 0; mt < 4; ++mt)
      #pragma unroll
      for (int dt = 0; dt < 2; ++dt) {
        int col = w * 32 + dt * 16 + l15;
        float cp = vec[256 + col];
        f32x4 a = accD[mt][dt];
        float s = fmaxf(a[0] + cp, 0.f) + fmaxf(a[1] + cp, 0.f)
                + fmaxf(a[2] + cp, 0.f) + fmaxf(a[3] + cp, 0.f);
        s += __shfl_xor(s, 16);
        int grow = mt * 2 + (lane >= 32 ? 1 : 0);
        if ((lane & 31) < 16) Sph[grow * LROW + col] = f2bf(s);
      }
  }
  __syncthreads();

  // ---- phase 6: ho = relu(Sph @ WO + cO)  (M=16 tile: 8 graphs + 8 zero rows)
  {
    f32x4 acco[2];
    f32x4 zero = {0.f, 0.f, 0.f, 0.f};
    acco[0] = zero; acco[1] = zero;
    #pragma unroll
    for (int kb = 0; kb < 128; kb += 32) {
      const int ko = kb + quad * 8;
      bf16x8 fa = *(const bf16x8*)&Sph[l15 * LROW + ko];
      #pragma unroll
      for (int dt = 0; dt < 2; ++dt) {
        bf16x8 fbv = *(const bf16x8*)&WoT[(w * 32 + dt * 16 + l15) * 128 + ko];
        acco[dt] = MFMA16(fa, fbv, acco[dt]);
      }
    }
    #pragma unroll
    for (int dt = 0; dt < 2; ++dt) {
      int col = w * 32 + dt * 16 + l15;
      float co = vec[384 + col];
      #pragma unroll
      for (int r = 0; r < 4; ++r)
        hob[(quad * 4 + r) * LROW + col] = f2bf(fmaxf(acco[dt][r] + co, 0.f));
    }
  }
  __syncthreads();

  // ---- phase 7: logits = ho @ out_W2 + out_b2  (wave 0 only)
  if (w == 0) {
    f32x4 accf = {0.f, 0.f, 0.f, 0.f};
    #pragma unroll
    for (int kb = 0; kb < 128; kb += 32) {
      const int ko = kb + quad * 8;
      bf16x8 fa  = *(const bf16x8*)&hob[l15 * LROW + ko];
      bf16x8 fbv = *(const bf16x8*)&Wo2T[l15 * 128 + ko];
      accf = MFMA16(fa, fbv, accf);
    }
    if (quad < 2) {
      float b2 = out_b2[l15];
      #pragma unroll
      for (int r = 0; r < 4; ++r) {
        int row = quad * 4 + r;                 // 0..7 -> graph within block
        out[(g0 + row) * 16 + l15] = accf[r] + b2;
      }
    }
  }
}

extern "C" void kernel_launch(void* const* d_in, const int* in_sizes, int n_in,
                              void* d_out, int out_size, void* d_ws, size_t ws_size,
                              hipStream_t stream) {
  const int*   anchors   = (const int*)d_in[0];
  const int*   n_jumps   = (const int*)d_in[1];
  const float* positions = (const float*)d_in[2];
  const int*   colors    = (const int*)d_in[3];
  const int*   markers   = (const int*)d_in[4];
  const float* pre_W1  = (const float*)d_in[5];
  const float* pre_b1  = (const float*)d_in[6];
  const float* pre_W2  = (const float*)d_in[7];
  const float* pre_b2  = (const float*)d_in[8];
  const float* msg_W1  = (const float*)d_in[9];
  const float* msg_b1  = (const float*)d_in[10];
  const float* msg_W2  = (const float*)d_in[11];
  const float* msg_b2  = (const float*)d_in[12];
  const float* post_W1 = (const float*)d_in[13];
  const float* post_b1 = (const float*)d_in[14];
  const float* post_W2 = (const float*)d_in[15];
  const float* post_b2 = (const float*)d_in[16];
  const float* out_W1  = (const float*)d_in[17];
  const float* out_b1  = (const float*)d_in[18];
  const float* out_W2  = (const float*)d_in[19];
  const float* out_b2  = (const float*)d_in[20];

  char* ws = (char*)d_ws;
  unsigned short* WabT = (unsigned short*)(ws);            // [256][128] bf16
  unsigned short* WdT  = (unsigned short*)(ws + 65536);    // [128][128]
  unsigned short* WcT  = (unsigned short*)(ws + 98304);    // [128][128]
  unsigned short* WoT  = (unsigned short*)(ws + 131072);   // [128][128]
  unsigned short* Wo2T = (unsigned short*)(ws + 163840);   // [16][128]
  float*          vecs = (float*)(ws + 167936);            // 512 f32

  const int BS = in_sizes[0];

  combine_weights<<<321, 256, 0, stream>>>(
      pre_W2, msg_W1, msg_W2, post_W1, post_W2, out_W1, out_W2,
      pre_b2, msg_b1, msg_b2, post_b1, post_b2, out_b1,
      WabT, WdT, WcT, WoT, Wo2T, vecs);

  rrn_main<<<BS / 8, 256, 0, stream>>>(
      anchors, n_jumps, positions, colors, markers, pre_W1, pre_b1,
      WabT, WdT, WcT, WoT, Wo2T, vecs, out_b2, (float*)d_out);
}

// Round 3
// 177.670 us; speedup vs baseline: 1.0813x; 1.0813x over previous
//
#include <hip/hip_runtime.h>

#define LROW 136   // padded LDS row stride in bf16 elements (128 + 8); 272 B = 16B-aligned rows

typedef __bf16 bf16x8 __attribute__((ext_vector_type(8)));
typedef float  f32x4  __attribute__((ext_vector_type(4)));

#define MFMA16(a, b, c) __builtin_amdgcn_mfma_f32_16x16x32_bf16((a), (b), (c), 0, 0, 0)

__device__ __forceinline__ unsigned short f2bf(float f) {
  unsigned u = __float_as_uint(f);
  u += 0x7fffu + ((u >> 16) & 1u);          // round-to-nearest-even
  return (unsigned short)(u >> 16);
}
__device__ __forceinline__ float bflo(unsigned v) { return __uint_as_float(v << 16); }
__device__ __forceinline__ float bfhi(unsigned v) { return __uint_as_float(v & 0xffff0000u); }

// ---------------------------------------------------------------------------
// Kernel 1: fold linear layers into combined weight matrices (bf16, transposed
// [n][k] layout) + folded bias vectors (f32). Bias reductions parallelized
// across blocks 321-323 (R2 post-mortem: serial 128-iter loop was ~90us).
//   WA = pre_W2 @ msg_W1[0:128]     WB = pre_W2 @ msg_W1[128:256]
//   WD = pre_W2 @ post_W1[128:256]  WC = msg_W2 @ post_W1[0:128]
//   WO = post_W2 @ out_W1           Wo2T = out_W2^T
//   vecs = [w1d | cAB | cP | cO]
// ---------------------------------------------------------------------------
__global__ void combine_weights(
    const float* __restrict__ pre_W2, const float* __restrict__ msg_W1,
    const float* __restrict__ msg_W2, const float* __restrict__ post_W1,
    const float* __restrict__ post_W2, const float* __restrict__ out_W1,
    const float* __restrict__ out_W2, const float* __restrict__ pre_b2,
    const float* __restrict__ msg_b1, const float* __restrict__ msg_b2,
    const float* __restrict__ post_b1, const float* __restrict__ post_b2,
    const float* __restrict__ out_b1,
    unsigned short* __restrict__ WabT, unsigned short* __restrict__ WdT,
    unsigned short* __restrict__ WcT, unsigned short* __restrict__ WoT,
    unsigned short* __restrict__ Wo2T, float* __restrict__ vecs)
{
  __shared__ float part[256];
  const int b = blockIdx.x;
  const int t = threadIdx.x;
  if (b < 320) {
    const int p  = b >> 6;            // which product
    const int kp = b & 63;            // k row-pair
    const int k  = kp * 2 + (t >> 7);
    const int n  = t & 127;
    const float* L; const float* R; unsigned short* O;
    if (p == 0)      { L = pre_W2;  R = msg_W1;             O = WabT; }
    else if (p == 1) { L = pre_W2;  R = msg_W1 + 128*128;   O = WabT + 128*128; }
    else if (p == 2) { L = pre_W2;  R = post_W1 + 128*128;  O = WdT; }
    else if (p == 3) { L = msg_W2;  R = post_W1;            O = WcT; }
    else             { L = post_W2; R = out_W1;             O = WoT; }
    const float* Lr = L + k * 128;
    float a0 = 0.f, a1 = 0.f, a2 = 0.f, a3 = 0.f;
    #pragma unroll 8
    for (int m = 0; m < 128; m += 4) {
      a0 = fmaf(Lr[m + 0], R[(m + 0) * 128 + n], a0);
      a1 = fmaf(Lr[m + 1], R[(m + 1) * 128 + n], a1);
      a2 = fmaf(Lr[m + 2], R[(m + 2) * 128 + n], a2);
      a3 = fmaf(Lr[m + 3], R[(m + 3) * 128 + n], a3);
    }
    O[n * 128 + k] = f2bf((a0 + a1) + (a2 + a3));
  } else if (b == 320) {
    // Wo2T transpose + w1d copy
    for (int idx = t; idx < 16 * 128; idx += 256) {
      int o = idx >> 7, k = idx & 127;
      Wo2T[o * 128 + k] = f2bf(out_W2[k * 16 + o]);
    }
    if (t < 128) vecs[t] = msg_W1[256 * 128 + t];          // w1d
  } else {
    // blocks 321..323: parallel bias reductions. n = t&127, half h = t>>7.
    const int n = t & 127;
    const int h = t >> 7;
    float s = 0.f;
    if (b == 321) {            // cAB = pre_b2@(W1a+W1b) + msg_b1
      #pragma unroll 8
      for (int m = h * 64; m < h * 64 + 64; ++m)
        s = fmaf(pre_b2[m], msg_W1[m * 128 + n] + msg_W1[(128 + m) * 128 + n], s);
    } else if (b == 322) {     // cP = 7*msg_b2@P1a + pre_b2@P1b + post_b1
      #pragma unroll 8
      for (int m = h * 64; m < h * 64 + 64; ++m) {
        s = fmaf(7.f * msg_b2[m], post_W1[m * 128 + n], s);
        s = fmaf(pre_b2[m], post_W1[(128 + m) * 128 + n], s);
      }
    } else {                   // cO = 8*post_b2@out_W1 + out_b1
      #pragma unroll 8
      for (int m = h * 64; m < h * 64 + 64; ++m)
        s = fmaf(8.f * post_b2[m], out_W1[m * 128 + n], s);
    }
    part[t] = s;
    __syncthreads();
    if (t < 128) {
      float r = part[t] + part[t + 128];
      if (b == 321)      vecs[128 + t] = r + msg_b1[t];
      else if (b == 322) vecs[256 + t] = r + post_b1[t];
      else               vecs[384 + t] = r + out_b1[t];
    }
  }
}

// ---------------------------------------------------------------------------
// Kernel 2: fully fused RRN. One block = 8 graphs = 64 node-rows.
// LDS = 54272 B -> 3 blocks/CU (was 65024 -> 2). S overwrites A in-place;
// Sph/hob reuse the h1 region; node data staged once in sW1 slack.
// ---------------------------------------------------------------------------
__global__ void __launch_bounds__(256, 3) rrn_main(
    const int* __restrict__ anchors, const int* __restrict__ n_jumps,
    const float* __restrict__ positions, const int* __restrict__ colors,
    const int* __restrict__ markers, const float* __restrict__ pre_W1,
    const float* __restrict__ pre_b1,
    const unsigned short* __restrict__ WabT, const unsigned short* __restrict__ WdT,
    const unsigned short* __restrict__ WcT, const unsigned short* __restrict__ WoT,
    const unsigned short* __restrict__ Wo2T, const float* __restrict__ vecs,
    const float* __restrict__ out_b2, float* __restrict__ out)
{
  __shared__ __align__(16) char smem[54272];
  // Region B [0, 34816): Ab [64][LROW] @0, Bb [64][LROW] @17408.
  //   Phases 0-1 alias: sW1 f32[43*128] @0 (22016 B), posL @22016, cmk @22528,
  //   ganj @22784 (all dead before phase-2 write-back).
  // Region A [34816, 52224): h1 [64][LROW] (phases 1-2); Sph @34816, hob @39168 (phases 5+).
  // dist f32[512] @52224 (persistent).
  unsigned short* Ab  = (unsigned short*)(smem);
  unsigned short* Bb  = (unsigned short*)(smem + 17408);
  float* sW1          = (float*)(smem);
  float* posL         = (float*)(smem + 22016);
  int*   cmk          = (int*)(smem + 22528);
  int*   ganj         = (int*)(smem + 22784);
  unsigned short* h1  = (unsigned short*)(smem + 34816);
  unsigned short* Sph = (unsigned short*)(smem + 34816);
  unsigned short* hob = (unsigned short*)(smem + 39168);
  float* dist         = (float*)(smem + 52224);

  const int tid  = threadIdx.x;
  const int lane = tid & 63;
  const int w    = tid >> 6;      // wave 0..3
  const int l15  = lane & 15;
  const int quad = lane >> 4;
  const int g0   = blockIdx.x * 8;   // global graph base
  const int n0   = blockIdx.x * 64;  // global node base

  // ---- phase 0: stage pre_W1+b1, node data, pairwise distances
  for (int i = tid; i < 43 * 128; i += 256)
    sW1[i] = (i < 42 * 128) ? pre_W1[i] : pre_b1[i - 42 * 128];
  if (tid < 128) posL[tid] = positions[n0 * 2 + tid];
  else if (tid < 192) {
    int node = tid - 128;
    cmk[node] = colors[n0 + node] | ((markers[n0 + node] - 8) << 8);
  } else if (tid < 200) {
    int g = tid - 192;
    ganj[g] = anchors[g0 + g] | (n_jumps[g0 + g] << 8);
  }
  for (int i = tid; i < 512; i += 256) {
    int g = i >> 6, ii = (i >> 3) & 7, jj = i & 7;
    const float* pa = positions + (n0 + g * 8 + ii) * 2;
    const float* pb = positions + (n0 + g * 8 + jj) * 2;
    float dx = pa[0] - pb[0], dy = pa[1] - pb[1];
    dist[i] = sqrtf(dx * dx + dy * dy);
  }
  __syncthreads();

  // ---- phase 1: h1 = relu(feat @ pre_W1 + pre_b1) via one-hot gathers (LDS-only)
  {
    const int n  = tid & 127;
    const int rh = tid >> 7;
    for (int rr = 0; rr < 32; ++rr) {
      int r = rh * 32 + rr;
      float px = posL[r * 2], py = posL[r * 2 + 1];
      int cm = cmk[r], gn = ganj[r >> 3];
      int c = cm & 255, mk = cm >> 8;
      int a = gn & 255, nj = gn >> 8;
      float acc = sW1[42 * 128 + n]
                + px * sW1[n] + py * sW1[128 + n]
                + sW1[(2 + c) * 128 + n] + sW1[(10 + mk) * 128 + n]
                + sW1[(18 + a) * 128 + n] + sW1[(34 + nj) * 128 + n];
      h1[r * LROW + n] = f2bf(fmaxf(acc, 0.f));
    }
  }
  __syncthreads();

  // ---- phase 2: [A|B|D] = h1 @ [WA|WB|WD]   (M=64, N=384, K=128)
  f32x4 accAB[4][4];   // wave's 64 cols of A|B
  f32x4 accD[4][2];    // wave's 32 cols of D (lives until phase 5)
  {
    f32x4 zero = {0.f, 0.f, 0.f, 0.f};
    #pragma unroll
    for (int mt = 0; mt < 4; ++mt) {
      #pragma unroll
      for (int nt = 0; nt < 4; ++nt) accAB[mt][nt] = zero;
      accD[mt][0] = zero; accD[mt][1] = zero;
    }
  }
  #pragma unroll
  for (int kb = 0; kb < 128; kb += 32) {
    const int ko = kb + quad * 8;
    bf16x8 fa[4], fb[4], fd[2];
    #pragma unroll
    for (int mt = 0; mt < 4; ++mt)
      fa[mt] = *(const bf16x8*)&h1[(mt * 16 + l15) * LROW + ko];
    #pragma unroll
    for (int nt = 0; nt < 4; ++nt)
      fb[nt] = *(const bf16x8*)&WabT[(w * 64 + nt * 16 + l15) * 128 + ko];
    #pragma unroll
    for (int dt = 0; dt < 2; ++dt)
      fd[dt] = *(const bf16x8*)&WdT[(w * 32 + dt * 16 + l15) * 128 + ko];
    #pragma unroll
    for (int mt = 0; mt < 4; ++mt) {
      #pragma unroll
      for (int nt = 0; nt < 4; ++nt)
        accAB[mt][nt] = MFMA16(fa[mt], fb[nt], accAB[mt][nt]);
      accD[mt][0] = MFMA16(fa[mt], fd[0], accD[mt][0]);
      accD[mt][1] = MFMA16(fa[mt], fd[1], accD[mt][1]);
    }
  }
  {
    // write-back A (waves 0,1) / B (waves 2,3); overwrites dead sW1/posL/cmk/ganj
    unsigned short* dstbuf = (w < 2) ? Ab : Bb;
    const int cb = (w & 1) * 64;
    #pragma unroll
    for (int mt = 0; mt < 4; ++mt)
      #pragma unroll
      for (int nt = 0; nt < 4; ++nt) {
        int col = cb + nt * 16 + l15;
        #pragma unroll
        for (int r = 0; r < 4; ++r)
          dstbuf[(mt * 16 + quad * 4 + r) * LROW + col] = f2bf(accAB[mt][nt][r]);
      }
  }
  __syncthreads();

  // ---- phase 4: edges. S[i] = sum_{j!=i} relu(A[i]+B[j]+d_ij*w1d+cAB).
  //      S overwrites A in-place (each thread owns its (row, 4-col) slice).
  {
    const int g   = tid >> 5;          // graph 0..7
    const int nb4 = (tid & 31) * 4;    // 4 hidden dims per thread
    const float4 w1d4 = *(const float4*)&vecs[nb4];
    const float4 cab4 = *(const float4*)&vecs[128 + nb4];
    float B0[8], B1[8], B2[8], B3[8];
    #pragma unroll
    for (int j = 0; j < 8; ++j) {
      uint2 vb = *(const uint2*)&Bb[(g * 8 + j) * LROW + nb4];
      B0[j] = bflo(vb.x); B1[j] = bfhi(vb.x);
      B2[j] = bflo(vb.y); B3[j] = bfhi(vb.y);
    }
    #pragma unroll
    for (int i = 0; i < 8; ++i) {
      uint2 va = *(const uint2*)&Ab[(g * 8 + i) * LROW + nb4];
      float a0 = bflo(va.x) + cab4.x, a1 = bfhi(va.x) + cab4.y;
      float a2 = bflo(va.y) + cab4.z, a3 = bfhi(va.y) + cab4.w;
      float s0 = 0.f, s1 = 0.f, s2 = 0.f, s3 = 0.f;
      #pragma unroll
      for (int j = 0; j < 8; ++j) {
        if (j == i) continue;
        float d = dist[g * 64 + i * 8 + j];
        s0 += fmaxf(fmaf(d, w1d4.x, B0[j]) + a0, 0.f);
        s1 += fmaxf(fmaf(d, w1d4.y, B1[j]) + a1, 0.f);
        s2 += fmaxf(fmaf(d, w1d4.z, B2[j]) + a2, 0.f);
        s3 += fmaxf(fmaf(d, w1d4.w, B3[j]) + a3, 0.f);
      }
      uint2 o;
      o.x = (unsigned)f2bf(s0) | ((unsigned)f2bf(s1) << 16);
      o.y = (unsigned)f2bf(s2) | ((unsigned)f2bf(s3) << 16);
      *(uint2*)&Ab[(g * 8 + i) * LROW + nb4] = o;   // in-place
    }
  }
  __syncthreads();

  // ---- phase 5: ph = relu(S@Wc + D + cP); per-graph sum -> Sph (bf16, pad rows zeroed)
  {
    const unsigned short* Sb = Ab;
    #pragma unroll
    for (int kb = 0; kb < 128; kb += 32) {
      const int ko = kb + quad * 8;
      bf16x8 fa[4], fc[2];
      #pragma unroll
      for (int mt = 0; mt < 4; ++mt)
        fa[mt] = *(const bf16x8*)&Sb[(mt * 16 + l15) * LROW + ko];
      #pragma unroll
      for (int dt = 0; dt < 2; ++dt)
        fc[dt] = *(const bf16x8*)&WcT[(w * 32 + dt * 16 + l15) * 128 + ko];
      #pragma unroll
      for (int mt = 0; mt < 4; ++mt) {
        accD[mt][0] = MFMA16(fa[mt], fc[0], accD[mt][0]);
        accD[mt][1] = MFMA16(fa[mt], fc[1], accD[mt][1]);
      }
    }
    #pragma unroll
    for (int mt = 0; mt < 4; ++mt)
      #pragma unroll
      for (int dt = 0; dt < 2; ++dt) {
        int col = w * 32 + dt * 16 + l15;
        float cp = vecs[256 + col];
        f32x4 a = accD[mt][dt];
        float s = fmaxf(a[0] + cp, 0.f) + fmaxf(a[1] + cp, 0.f)
                + fmaxf(a[2] + cp, 0.f) + fmaxf(a[3] + cp, 0.f);
        s += __shfl_xor(s, 16);
        int grow = mt * 2 + (lane >= 32 ? 1 : 0);
        if ((lane & 31) < 16) Sph[grow * LROW + col] = f2bf(s);
        else                  Sph[(8 + grow) * LROW + col] = 0;   // zero pad rows 8..15
      }
  }
  __syncthreads();

  // ---- phase 6: ho = relu(Sph @ WO + cO)  (M=16 tile: 8 graphs + 8 zero rows)
  {
    f32x4 acco[2];
    f32x4 zero = {0.f, 0.f, 0.f, 0.f};
    acco[0] = zero; acco[1] = zero;
    #pragma unroll
    for (int kb = 0; kb < 128; kb += 32) {
      const int ko = kb + quad * 8;
      bf16x8 fa = *(const bf16x8*)&Sph[l15 * LROW + ko];
      #pragma unroll
      for (int dt = 0; dt < 2; ++dt) {
        bf16x8 fbv = *(const bf16x8*)&WoT[(w * 32 + dt * 16 + l15) * 128 + ko];
        acco[dt] = MFMA16(fa, fbv, acco[dt]);
      }
    }
    #pragma unroll
    for (int dt = 0; dt < 2; ++dt) {
      int col = w * 32 + dt * 16 + l15;
      float co = vecs[384 + col];
      #pragma unroll
      for (int r = 0; r < 4; ++r)
        hob[(quad * 4 + r) * LROW + col] = f2bf(fmaxf(acco[dt][r] + co, 0.f));
    }
  }
  __syncthreads();

  // ---- phase 7: logits = ho @ out_W2 + out_b2  (wave 0 only)
  if (w == 0) {
    f32x4 accf = {0.f, 0.f, 0.f, 0.f};
    #pragma unroll
    for (int kb = 0; kb < 128; kb += 32) {
      const int ko = kb + quad * 8;
      bf16x8 fa  = *(const bf16x8*)&hob[l15 * LROW + ko];
      bf16x8 fbv = *(const bf16x8*)&Wo2T[l15 * 128 + ko];
      accf = MFMA16(fa, fbv, accf);
    }
    if (quad < 2) {
      float b2 = out_b2[l15];
      #pragma unroll
      for (int r = 0; r < 4; ++r) {
        int row = quad * 4 + r;                 // 0..7 -> graph within block
        out[(g0 + row) * 16 + l15] = accf[r] + b2;
      }
    }
  }
}

extern "C" void kernel_launch(void* const* d_in, const int* in_sizes, int n_in,
                              void* d_out, int out_size, void* d_ws, size_t ws_size,
                              hipStream_t stream) {
  const int*   anchors   = (const int*)d_in[0];
  const int*   n_jumps   = (const int*)d_in[1];
  const float* positions = (const float*)d_in[2];
  const int*   colors    = (const int*)d_in[3];
  const int*   markers   = (const int*)d_in[4];
  const float* pre_W1  = (const float*)d_in[5];
  const float* pre_b1  = (const float*)d_in[6];
  const float* pre_W2  = (const float*)d_in[7];
  const float* pre_b2  = (const float*)d_in[8];
  const float* msg_W1  = (const float*)d_in[9];
  const float* msg_b1  = (const float*)d_in[10];
  const float* msg_W2  = (const float*)d_in[11];
  const float* msg_b2  = (const float*)d_in[12];
  const float* post_W1 = (const float*)d_in[13];
  const float* post_b1 = (const float*)d_in[14];
  const float* post_W2 = (const float*)d_in[15];
  const float* post_b2 = (const float*)d_in[16];
  const float* out_W1  = (const float*)d_in[17];
  const float* out_b1  = (const float*)d_in[18];
  const float* out_W2  = (const float*)d_in[19];
  const float* out_b2  = (const float*)d_in[20];

  char* ws = (char*)d_ws;
  unsigned short* WabT = (unsigned short*)(ws);            // [256][128] bf16
  unsigned short* WdT  = (unsigned short*)(ws + 65536);    // [128][128]
  unsigned short* WcT  = (unsigned short*)(ws + 98304);    // [128][128]
  unsigned short* WoT  = (unsigned short*)(ws + 131072);   // [128][128]
  unsigned short* Wo2T = (unsigned short*)(ws + 163840);   // [16][128]
  float*          vecs = (float*)(ws + 167936);            // 512 f32

  const int BS = in_sizes[0];

  combine_weights<<<324, 256, 0, stream>>>(
      pre_W2, msg_W1, msg_W2, post_W1, post_W2, out_W1, out_W2,
      pre_b2, msg_b1, msg_b2, post_b1, post_b2, out_b1,
      WabT, WdT, WcT, WoT, Wo2T, vecs);

  rrn_main<<<BS / 8, 256, 0, stream>>>(
      anchors, n_jumps, positions, colors, markers, pre_W1, pre_b1,
      WabT, WdT, WcT, WoT, Wo2T, vecs, out_b2, (float*)d_out);
}

// Round 4
// 155.849 us; speedup vs baseline: 1.2327x; 1.1400x over previous
//
#include <hip/hip_runtime.h>

#define LROW 136   // padded LDS row stride in bf16 elements (128 + 8); 272 B rows

typedef __bf16 bf16x8  __attribute__((ext_vector_type(8)));
typedef __bf16 bf16x4v __attribute__((ext_vector_type(4)));
typedef float  f32x4   __attribute__((ext_vector_type(4)));

#define MFMA16(a, b, c) __builtin_amdgcn_mfma_f32_16x16x32_bf16((a), (b), (c), 0, 0, 0)

__device__ __forceinline__ float bflo(unsigned v) { return __uint_as_float(v << 16); }
__device__ __forceinline__ float bfhi(unsigned v) { return __uint_as_float(v & 0xffff0000u); }

__device__ __forceinline__ unsigned short f2bf_u16(float f) {
  unsigned u = __float_as_uint(f);
  u += 0x7fffu + ((u >> 16) & 1u);
  return (unsigned short)(u >> 16);
}

// ---------------------------------------------------------------------------
// Kernel 1: fold linear layers into combined weight matrices (bf16, [n][k]
// transposed layout) + folded bias vectors (f32). Bias reductions parallel
// (blocks 321-323).
//   WA = pre_W2 @ msg_W1[0:128]     WB = pre_W2 @ msg_W1[128:256]
//   WD = pre_W2 @ post_W1[128:256]  WC = msg_W2 @ post_W1[0:128]
//   WO = post_W2 @ out_W1           Wo2T = out_W2^T
//   vecs = [w1d | cAB | cP | cO]
// ---------------------------------------------------------------------------
__global__ void combine_weights(
    const float* __restrict__ pre_W2, const float* __restrict__ msg_W1,
    const float* __restrict__ msg_W2, const float* __restrict__ post_W1,
    const float* __restrict__ post_W2, const float* __restrict__ out_W1,
    const float* __restrict__ out_W2, const float* __restrict__ pre_b2,
    const float* __restrict__ msg_b1, const float* __restrict__ msg_b2,
    const float* __restrict__ post_b1, const float* __restrict__ post_b2,
    const float* __restrict__ out_b1,
    unsigned short* __restrict__ WabT, unsigned short* __restrict__ WdT,
    unsigned short* __restrict__ WcT, unsigned short* __restrict__ WoT,
    unsigned short* __restrict__ Wo2T, float* __restrict__ vecs)
{
  __shared__ float part[256];
  const int b = blockIdx.x;
  const int t = threadIdx.x;
  if (b < 320) {
    const int p  = b >> 6;
    const int kp = b & 63;
    const int k  = kp * 2 + (t >> 7);
    const int n  = t & 127;
    const float* L; const float* R; unsigned short* O;
    if (p == 0)      { L = pre_W2;  R = msg_W1;             O = WabT; }
    else if (p == 1) { L = pre_W2;  R = msg_W1 + 128*128;   O = WabT + 128*128; }
    else if (p == 2) { L = pre_W2;  R = post_W1 + 128*128;  O = WdT; }
    else if (p == 3) { L = msg_W2;  R = post_W1;            O = WcT; }
    else             { L = post_W2; R = out_W1;             O = WoT; }
    const float* Lr = L + k * 128;
    float a0 = 0.f, a1 = 0.f, a2 = 0.f, a3 = 0.f;
    #pragma unroll 8
    for (int m = 0; m < 128; m += 4) {
      a0 = fmaf(Lr[m + 0], R[(m + 0) * 128 + n], a0);
      a1 = fmaf(Lr[m + 1], R[(m + 1) * 128 + n], a1);
      a2 = fmaf(Lr[m + 2], R[(m + 2) * 128 + n], a2);
      a3 = fmaf(Lr[m + 3], R[(m + 3) * 128 + n], a3);
    }
    O[n * 128 + k] = f2bf_u16((a0 + a1) + (a2 + a3));
  } else if (b == 320) {
    for (int idx = t; idx < 16 * 128; idx += 256) {
      int o = idx >> 7, k = idx & 127;
      Wo2T[o * 128 + k] = f2bf_u16(out_W2[k * 16 + o]);
    }
    if (t < 128) vecs[t] = msg_W1[256 * 128 + t];          // w1d
  } else {
    const int n = t & 127;
    const int h = t >> 7;
    float s = 0.f;
    if (b == 321) {            // cAB = pre_b2@(W1a+W1b) + msg_b1
      #pragma unroll 8
      for (int m = h * 64; m < h * 64 + 64; ++m)
        s = fmaf(pre_b2[m], msg_W1[m * 128 + n] + msg_W1[(128 + m) * 128 + n], s);
    } else if (b == 322) {     // cP = 7*msg_b2@P1a + pre_b2@P1b + post_b1
      #pragma unroll 8
      for (int m = h * 64; m < h * 64 + 64; ++m) {
        s = fmaf(7.f * msg_b2[m], post_W1[m * 128 + n], s);
        s = fmaf(pre_b2[m], post_W1[(128 + m) * 128 + n], s);
      }
    } else {                   // cO = 8*post_b2@out_W1 + out_b1
      #pragma unroll 8
      for (int m = h * 64; m < h * 64 + 64; ++m)
        s = fmaf(8.f * post_b2[m], out_W1[m * 128 + n], s);
    }
    part[t] = s;
    __syncthreads();
    if (t < 128) {
      float r = part[t] + part[t + 128];
      if (b == 321)      vecs[128 + t] = r + msg_b1[t];
      else if (b == 322) vecs[256 + t] = r + post_b1[t];
      else               vecs[384 + t] = r + out_b1[t];
    }
  }
}

// ---------------------------------------------------------------------------
// Kernel 2: fully fused RRN. One block = 8 graphs = 64 node-rows.
// R3 post-mortem: occupancy was capped at 2 blocks/CU by combined VGPR+AGPR
// (~180 > 128), not LDS. Redesign: phase-2 split into A|B pass (16 accs) +
// D pass (8 accs) so peak live accs = 64 regs; LDS 38912 B; launch_bounds
// (256,4) -> 4 blocks/CU.
// ---------------------------------------------------------------------------
__global__ void __launch_bounds__(256, 4) rrn_main(
    const int* __restrict__ anchors, const int* __restrict__ n_jumps,
    const float* __restrict__ positions, const int* __restrict__ colors,
    const int* __restrict__ markers, const float* __restrict__ pre_W1,
    const float* __restrict__ pre_b1,
    const __bf16* __restrict__ WabT, const __bf16* __restrict__ WdT,
    const __bf16* __restrict__ WcT, const __bf16* __restrict__ WoT,
    const __bf16* __restrict__ Wo2T, const float* __restrict__ vecs,
    const float* __restrict__ out_b2, float* __restrict__ out)
{
  __shared__ __align__(16) char smem[38912];
  // R0 [0,17408): phases 0-1: sW1s[18*128] f32 @0, qrow[8*128] f32 @9216,
  //               posL @13312, cmk @13824. Phase 2+: Ab [64][LROW] (A, then S in place).
  // R1 [17408,34816): h1 [64][LROW] (phases 1-2); Bb (B) after pass D;
  //               Sph @17408 / hob @21760 (phases 5+).
  // dist f32[512] @34816; vec f32[512] @36864.
  __bf16* Ab   = (__bf16*)(smem);
  float*  sW1s = (float*)(smem);
  float*  qrow = (float*)(smem + 9216);
  float*  posL = (float*)(smem + 13312);
  int*    cmk  = (int*)(smem + 13824);
  __bf16* h1   = (__bf16*)(smem + 17408);
  __bf16* Bb   = (__bf16*)(smem + 17408);
  __bf16* Sph  = (__bf16*)(smem + 17408);
  __bf16* hob  = (__bf16*)(smem + 21760);
  float*  dist = (float*)(smem + 34816);
  float*  vec  = (float*)(smem + 36864);

  const int tid  = threadIdx.x;
  const int lane = tid & 63;
  const int w    = tid >> 6;      // wave 0..3
  const int l15  = lane & 15;
  const int quad = lane >> 4;
  const int colw = w * 32;        // this wave's 32-col slice of A/B/D/ph
  const int g0   = blockIdx.x * 8;
  const int n0   = blockIdx.x * 64;

  // ---- phase 0: stage pre_W1 rows 0..17, per-graph qrow, node data, dist, vec
  for (int i = tid; i < 18 * 128; i += 256) sW1s[i] = pre_W1[i];
  {
    const int n = tid & 127;
    for (int g = (tid >> 7); g < 8; g += 2) {
      int a = anchors[g0 + g], nj = n_jumps[g0 + g];
      qrow[g * 128 + n] = pre_b1[n] + pre_W1[(18 + a) * 128 + n]
                        + pre_W1[(34 + nj) * 128 + n];
    }
  }
  if (tid < 128) posL[tid] = positions[n0 * 2 + tid];
  else if (tid < 192) {
    int node = tid - 128;
    cmk[node] = colors[n0 + node] | ((markers[n0 + node] - 8) << 8);
  }
  for (int i = tid; i < 512; i += 256) {
    int g = i >> 6, ii = (i >> 3) & 7, jj = i & 7;
    const float* pa = positions + (n0 + g * 8 + ii) * 2;
    const float* pb = positions + (n0 + g * 8 + jj) * 2;
    float dx = pa[0] - pb[0], dy = pa[1] - pb[1];
    dist[i] = sqrtf(dx * dx + dy * dy);
  }
  for (int i = tid; i < 512; i += 256) vec[i] = vecs[i];
  __syncthreads();

  // ---- phase 1: h1 = relu(feat @ pre_W1 + pre_b1) via one-hot gathers (LDS-only)
  {
    const int n  = tid & 127;
    const int rh = tid >> 7;
    for (int rr = 0; rr < 32; ++rr) {
      int r = rh * 32 + rr;
      float px = posL[r * 2], py = posL[r * 2 + 1];
      int cm = cmk[r];
      int c = cm & 255, mk = cm >> 8;
      float acc = qrow[(r >> 3) * 128 + n]
                + px * sW1s[n] + py * sW1s[128 + n]
                + sW1s[(2 + c) * 128 + n] + sW1s[(10 + mk) * 128 + n];
      h1[r * LROW + n] = (__bf16)fmaxf(acc, 0.f);
    }
  }
  __syncthreads();

  // ---- phase 2 pass 1: [A|B] cols colw..colw+31 each = h1 @ WabT (16 accs)
  f32x4 acc1[4][4];   // nt 0,1 -> A cols colw+nt*16; nt 2,3 -> B cols colw+(nt-2)*16
  {
    f32x4 zero = {0.f, 0.f, 0.f, 0.f};
    #pragma unroll
    for (int mt = 0; mt < 4; ++mt)
      #pragma unroll
      for (int nt = 0; nt < 4; ++nt) acc1[mt][nt] = zero;
  }
  #pragma unroll
  for (int kb = 0; kb < 128; kb += 32) {
    const int ko = kb + quad * 8;
    bf16x8 fa[4], fb[4];
    #pragma unroll
    for (int mt = 0; mt < 4; ++mt)
      fa[mt] = *(const bf16x8*)&h1[(mt * 16 + l15) * LROW + ko];
    fb[0] = *(const bf16x8*)&WabT[(colw + l15) * 128 + ko];
    fb[1] = *(const bf16x8*)&WabT[(colw + 16 + l15) * 128 + ko];
    fb[2] = *(const bf16x8*)&WabT[(128 + colw + l15) * 128 + ko];
    fb[3] = *(const bf16x8*)&WabT[(128 + colw + 16 + l15) * 128 + ko];
    #pragma unroll
    for (int mt = 0; mt < 4; ++mt)
      #pragma unroll
      for (int nt = 0; nt < 4; ++nt)
        acc1[mt][nt] = MFMA16(fa[mt], fb[nt], acc1[mt][nt]);
  }
  // write back A now (R0 is dead since the phase-1 barrier)
  #pragma unroll
  for (int mt = 0; mt < 4; ++mt)
    #pragma unroll
    for (int nt = 0; nt < 2; ++nt) {
      int col = colw + nt * 16 + l15;
      #pragma unroll
      for (int r = 0; r < 4; ++r)
        Ab[(mt * 16 + quad * 4 + r) * LROW + col] = (__bf16)acc1[mt][nt][r];
    }

  // ---- phase 2 pass 2: D cols colw..colw+31 = h1 @ WdT (8 accs, live to phase 5)
  f32x4 accD[4][2];
  {
    f32x4 zero = {0.f, 0.f, 0.f, 0.f};
    #pragma unroll
    for (int mt = 0; mt < 4; ++mt) { accD[mt][0] = zero; accD[mt][1] = zero; }
  }
  #pragma unroll
  for (int kb = 0; kb < 128; kb += 32) {
    const int ko = kb + quad * 8;
    bf16x8 fa[4], fd[2];
    #pragma unroll
    for (int mt = 0; mt < 4; ++mt)
      fa[mt] = *(const bf16x8*)&h1[(mt * 16 + l15) * LROW + ko];
    fd[0] = *(const bf16x8*)&WdT[(colw + l15) * 128 + ko];
    fd[1] = *(const bf16x8*)&WdT[(colw + 16 + l15) * 128 + ko];
    #pragma unroll
    for (int mt = 0; mt < 4; ++mt) {
      accD[mt][0] = MFMA16(fa[mt], fd[0], accD[mt][0]);
      accD[mt][1] = MFMA16(fa[mt], fd[1], accD[mt][1]);
    }
  }
  __syncthreads();   // all waves done reading h1
  // write back B over the dead h1 region
  #pragma unroll
  for (int mt = 0; mt < 4; ++mt)
    #pragma unroll
    for (int nt = 2; nt < 4; ++nt) {
      int col = colw + (nt - 2) * 16 + l15;
      #pragma unroll
      for (int r = 0; r < 4; ++r)
        Bb[(mt * 16 + quad * 4 + r) * LROW + col] = (__bf16)acc1[mt][nt][r];
    }
  __syncthreads();

  // ---- phase 4: edges. S[i] = sum_{j!=i} relu(A[i]+B[j]+d_ij*w1d+cAB).
  //      S overwrites A in-place (each thread owns its (row, 4-col) slice).
  {
    const int g   = tid >> 5;          // graph 0..7
    const int nb4 = (tid & 31) * 4;    // 4 hidden dims per thread
    const float4 w1d4 = *(const float4*)&vec[nb4];
    const float4 cab4 = *(const float4*)&vec[128 + nb4];
    float B0[8], B1[8], B2[8], B3[8];
    #pragma unroll
    for (int j = 0; j < 8; ++j) {
      uint2 vb = *(const uint2*)&Bb[(g * 8 + j) * LROW + nb4];
      B0[j] = bflo(vb.x); B1[j] = bfhi(vb.x);
      B2[j] = bflo(vb.y); B3[j] = bfhi(vb.y);
    }
    #pragma unroll
    for (int i = 0; i < 8; ++i) {
      uint2 va = *(const uint2*)&Ab[(g * 8 + i) * LROW + nb4];
      float a0 = bflo(va.x) + cab4.x, a1 = bfhi(va.x) + cab4.y;
      float a2 = bflo(va.y) + cab4.z, a3 = bfhi(va.y) + cab4.w;
      float s0 = 0.f, s1 = 0.f, s2 = 0.f, s3 = 0.f;
      #pragma unroll
      for (int j = 0; j < 8; ++j) {
        if (j == i) continue;
        float d = dist[g * 64 + i * 8 + j];
        s0 += fmaxf(fmaf(d, w1d4.x, B0[j]) + a0, 0.f);
        s1 += fmaxf(fmaf(d, w1d4.y, B1[j]) + a1, 0.f);
        s2 += fmaxf(fmaf(d, w1d4.z, B2[j]) + a2, 0.f);
        s3 += fmaxf(fmaf(d, w1d4.w, B3[j]) + a3, 0.f);
      }
      bf16x4v o = { (__bf16)s0, (__bf16)s1, (__bf16)s2, (__bf16)s3 };
      *(bf16x4v*)&Ab[(g * 8 + i) * LROW + nb4] = o;   // in-place
    }
  }
  __syncthreads();

  // ---- phase 5: ph = relu(S@Wc + D + cP); per-graph sum -> Sph (pad rows zeroed)
  {
    const __bf16* Sb = Ab;
    #pragma unroll
    for (int kb = 0; kb < 128; kb += 32) {
      const int ko = kb + quad * 8;
      bf16x8 fa[4], fc[2];
      #pragma unroll
      for (int mt = 0; mt < 4; ++mt)
        fa[mt] = *(const bf16x8*)&Sb[(mt * 16 + l15) * LROW + ko];
      fc[0] = *(const bf16x8*)&WcT[(colw + l15) * 128 + ko];
      fc[1] = *(const bf16x8*)&WcT[(colw + 16 + l15) * 128 + ko];
      #pragma unroll
      for (int mt = 0; mt < 4; ++mt) {
        accD[mt][0] = MFMA16(fa[mt], fc[0], accD[mt][0]);
        accD[mt][1] = MFMA16(fa[mt], fc[1], accD[mt][1]);
      }
    }
    #pragma unroll
    for (int mt = 0; mt < 4; ++mt)
      #pragma unroll
      for (int dt = 0; dt < 2; ++dt) {
        int col = colw + dt * 16 + l15;
        float cp = vec[256 + col];
        f32x4 a = accD[mt][dt];
        float s = fmaxf(a[0] + cp, 0.f) + fmaxf(a[1] + cp, 0.f)
                + fmaxf(a[2] + cp, 0.f) + fmaxf(a[3] + cp, 0.f);
        s += __shfl_xor(s, 16);
        int grow = mt * 2 + (lane >= 32 ? 1 : 0);
        if ((lane & 31) < 16) Sph[grow * LROW + col] = (__bf16)s;
        else                  Sph[(8 + grow) * LROW + col] = (__bf16)0.f;
      }
  }
  __syncthreads();

  // ---- phase 6: ho = relu(Sph @ WO + cO)  (M=16 tile: 8 graphs + 8 zero rows)
  {
    f32x4 acco[2];
    f32x4 zero = {0.f, 0.f, 0.f, 0.f};
    acco[0] = zero; acco[1] = zero;
    #pragma unroll
    for (int kb = 0; kb < 128; kb += 32) {
      const int ko = kb + quad * 8;
      bf16x8 fa = *(const bf16x8*)&Sph[l15 * LROW + ko];
      bf16x8 fb0 = *(const bf16x8*)&WoT[(colw + l15) * 128 + ko];
      bf16x8 fb1 = *(const bf16x8*)&WoT[(colw + 16 + l15) * 128 + ko];
      acco[0] = MFMA16(fa, fb0, acco[0]);
      acco[1] = MFMA16(fa, fb1, acco[1]);
    }
    #pragma unroll
    for (int dt = 0; dt < 2; ++dt) {
      int col = colw + dt * 16 + l15;
      float co = vec[384 + col];
      #pragma unroll
      for (int r = 0; r < 4; ++r)
        hob[(quad * 4 + r) * LROW + col] = (__bf16)fmaxf(acco[dt][r] + co, 0.f);
    }
  }
  __syncthreads();

  // ---- phase 7: logits = ho @ out_W2 + out_b2  (wave 0 only)
  if (w == 0) {
    f32x4 accf = {0.f, 0.f, 0.f, 0.f};
    #pragma unroll
    for (int kb = 0; kb < 128; kb += 32) {
      const int ko = kb + quad * 8;
      bf16x8 fa  = *(const bf16x8*)&hob[l15 * LROW + ko];
      bf16x8 fbv = *(const bf16x8*)&Wo2T[l15 * 128 + ko];
      accf = MFMA16(fa, fbv, accf);
    }
    if (quad < 2) {
      float b2 = out_b2[l15];
      #pragma unroll
      for (int r = 0; r < 4; ++r) {
        int row = quad * 4 + r;
        out[(g0 + row) * 16 + l15] = accf[r] + b2;
      }
    }
  }
}

extern "C" void kernel_launch(void* const* d_in, const int* in_sizes, int n_in,
                              void* d_out, int out_size, void* d_ws, size_t ws_size,
                              hipStream_t stream) {
  const int*   anchors   = (const int*)d_in[0];
  const int*   n_jumps   = (const int*)d_in[1];
  const float* positions = (const float*)d_in[2];
  const int*   colors    = (const int*)d_in[3];
  const int*   markers   = (const int*)d_in[4];
  const float* pre_W1  = (const float*)d_in[5];
  const float* pre_b1  = (const float*)d_in[6];
  const float* pre_W2  = (const float*)d_in[7];
  const float* pre_b2  = (const float*)d_in[8];
  const float* msg_W1  = (const float*)d_in[9];
  const float* msg_b1  = (const float*)d_in[10];
  const float* msg_W2  = (const float*)d_in[11];
  const float* msg_b2  = (const float*)d_in[12];
  const float* post_W1 = (const float*)d_in[13];
  const float* post_b1 = (const float*)d_in[14];
  const float* post_W2 = (const float*)d_in[15];
  const float* post_b2 = (const float*)d_in[16];
  const float* out_W1  = (const float*)d_in[17];
  const float* out_b1  = (const float*)d_in[18];
  const float* out_W2  = (const float*)d_in[19];
  const float* out_b2  = (const float*)d_in[20];

  char* ws = (char*)d_ws;
  unsigned short* WabT = (unsigned short*)(ws);            // [256][128] bf16
  unsigned short* WdT  = (unsigned short*)(ws + 65536);    // [128][128]
  unsigned short* WcT  = (unsigned short*)(ws + 98304);    // [128][128]
  unsigned short* WoT  = (unsigned short*)(ws + 131072);   // [128][128]
  unsigned short* Wo2T = (unsigned short*)(ws + 163840);   // [16][128]
  float*          vecs = (float*)(ws + 167936);            // 512 f32

  const int BS = in_sizes[0];

  combine_weights<<<324, 256, 0, stream>>>(
      pre_W2, msg_W1, msg_W2, post_W1, post_W2, out_W1, out_W2,
      pre_b2, msg_b1, msg_b2, post_b1, post_b2, out_b1,
      WabT, WdT, WcT, WoT, Wo2T, vecs);

  rrn_main<<<BS / 8, 256, 0, stream>>>(
      anchors, n_jumps, positions, colors, markers, pre_W1, pre_b1,
      (const __bf16*)WabT, (const __bf16*)WdT, (const __bf16*)WcT,
      (const __bf16*)WoT, (const __bf16*)Wo2T, vecs, out_b2, (float*)d_out);
}